// Round 3
// baseline (421.625 us; speedup 1.0000x reference)
//
#include <hip/hip_runtime.h>

// ---------------------------------------------------------------------------
// GCN 2-layer forward, round 15.
// Round-14 post-mortem: WIN 213.8->201.3us, but k_part still ~33us (by
// subtraction; only k_part changed). Fitting dur = k*chainDepth + M across
// rounds 13/14 gives chain ~4us and a ~29us floor: the bcur global atomic's
// cross-XCD same-line latency is amplified because all blocks sit at the
// same phase and each waits for its own atomic before __syncthreads.
// Counters (r13): HBM 10.8%, VALU 2.1% -> stall, not throughput.
// Round-15 delta: DELETE the global atomic. Static bases via 3 kernels:
//   * k_count: per-tile LDS histogram -> tcnt[b][tile] (reads coli only).
//   * k_scan: 1 block, thread-per-bucket exclusive scan of 416 tile counts
//     -> deterministic bases in-place + btot[b].
//   * k_scatter: LDS cursors from tcnt, one pass, LDS-atomic rank, write
//     pairs. No global atomics anywhere in partition. 2KB LDS, PTILE=4096.
// k_binit deleted; k_bfill takes m = btot[b]. gemm/agg byte-identical.
// Pipeline: count, scan, scatter, bfill, gemm1, agg1, gemm2, agg2.
// ---------------------------------------------------------------------------

#define NPB 32       // nodes per block (agg): 256 thr / 8-lane groups
#define BSH 8        // bucket shift: 256 nodes per bucket
#define BSZ 256
#define PTILE 4096   // messages per partition tile
#define CAP 6144     // fixed bucket capacity (slots), multiple of 16
#define PADALLOW 3856  // per-bucket csrc pad allowance (256*15 + 16)
#define CROW (CAP + PADALLOW)  // per-bucket csrc region

typedef __attribute__((ext_vector_type(8))) short bf16x8;
typedef __attribute__((ext_vector_type(4))) float f32x4;

__device__ __forceinline__ unsigned bf16_rne(float f) {
    unsigned b = __float_as_uint(f);
    return (b + 0x7fffu + ((b >> 16) & 1u)) >> 16;
}
__device__ __forceinline__ float bf16_lo(unsigned u) { return __uint_as_float(u << 16); }
__device__ __forceinline__ float bf16_hi(unsigned u) { return __uint_as_float(u & 0xffff0000u); }

// Per-tile bucket histogram. tcnt layout: [bucket][tile] (bucket-major so
// k_scan walks contiguous memory).
__global__ __launch_bounds__(256) void k_count(const int* __restrict__ coli,
                                               int E, int N, int NB, int numTiles,
                                               int* __restrict__ tcnt) {
    __shared__ int hist[512];
    int t = threadIdx.x;
    int T = E + N;
    int tile = blockIdx.x;
    int tstart = tile * PTILE;
    int m = min(PTILE, T - tstart);
    for (int b = t; b < NB; b += 256) hist[b] = 0;
    __syncthreads();
    for (int i = t; i < m; i += 256) {
        int g = tstart + i;
        int c = (g < E) ? coli[g] : (g - E);
        atomicAdd(&hist[c >> BSH], 1);
    }
    __syncthreads();
    for (int b = t; b < NB; b += 256) tcnt[(size_t)b * numTiles + tile] = hist[b];
}

// Exclusive scan per bucket over tiles: tcnt[b][t] <- b*CAP + prefix.
// Also emits total message count per bucket. One block; thread-per-bucket
// walks 416 contiguous ints (loads pipeline ahead of the add chain).
__global__ __launch_bounds__(512) void k_scan(int* __restrict__ tcnt,
                                              int* __restrict__ btot,
                                              int NB, int numTiles) {
    int b = threadIdx.x;
    if (b >= NB) return;
    int* p = tcnt + (size_t)b * numTiles;
    int base = b * CAP;
    for (int t2 = 0; t2 < numTiles; t2++) {
        int c = p[t2];
        p[t2] = base;
        base += c;
    }
    btot[b] = base - b * CAP;
}

// Scatter pass: LDS cursors seeded from scanned bases; LDS-atomic rank;
// contiguous-per-(tile,bucket) writes into pairs. No global atomics.
__global__ __launch_bounds__(256) void k_scatter(const int* __restrict__ rowi,
                                                 const int* __restrict__ coli,
                                                 int E, int N, int NB, int numTiles,
                                                 const int* __restrict__ tcnt,
                                                 unsigned* __restrict__ pairs) {
    __shared__ int scur[512];
    int t = threadIdx.x;
    int T = E + N;
    int tile = blockIdx.x;
    int tstart = tile * PTILE;
    int m = min(PTILE, T - tstart);
    for (int b = t; b < NB; b += 256) scur[b] = tcnt[(size_t)b * numTiles + tile];
    __syncthreads();
    for (int i = t; i < m; i += 256) {
        int g = tstart + i;
        int r, c;
        if (g < E) { r = rowi[g]; c = coli[g]; }
        else       { r = g - E; c = r; }  // self loop
        int b = c >> BSH;
        int slot = atomicAdd(&scur[b], 1);
        pairs[slot] = (unsigned)r | ((unsigned)(c & (BSZ - 1)) << 24);
    }
}

// One block per bucket (1024 threads): histogram its <=256 nodes, scan PADDED
// counts (16-aligned offsets), emit CSR meta (cnt = true count rounded to x2),
// fill csrc + sentinel pads. Message count for bucket b = btot[b].
__global__ __launch_bounds__(1024) void k_bfill(const unsigned* __restrict__ pairs,
                                                const int* __restrict__ btot,
                                                int N,
                                                int* __restrict__ offsets,
                                                int* __restrict__ cnt,
                                                float* __restrict__ dinv,
                                                int* __restrict__ csrc) {
    __shared__ int scnt[BSZ];
    __shared__ int scur[BSZ];
    __shared__ int wsum[4];
    int b = blockIdx.x;
    int t = threadIdx.x;
    int ebeg = b * CAP;
    int m = btot[b];
    int pbase = b * CROW;  // 16-aligned per-bucket csrc region base
    if (t < BSZ) scnt[t] = 0;
    __syncthreads();
    for (int i = t; i < m; i += 1024) {
        atomicAdd(&scnt[pairs[ebeg + i] >> 24], 1);
    }
    __syncthreads();
    int cval = 0, pc = 0, inc = 0;
    int lane = t & 63, wid = t >> 6;
    if (t < BSZ) {
        cval = scnt[t];                 // true msg count (incl. self loop)
        pc = (cval + 15) & ~15;         // offset padding: multiple of 16
        inc = pc;
        #pragma unroll
        for (int d = 1; d < 64; d <<= 1) {
            int o = __shfl_up(inc, d);
            if (lane >= d) inc += o;
        }
        if (lane == 63) wsum[wid] = inc;
    }
    __syncthreads();
    if (t < BSZ) {
        int woff = 0;
        for (int i = 0; i < wid; i++) woff += wsum[i];
        int off = pbase + woff + inc - pc;  // padded CSR offset for node (b<<BSH)+t
        int v = (b << BSH) + t;
        if (v < N) {
            offsets[v] = off;
            cnt[v] = (cval + 1) & ~1;       // round to x2 for int2 agg loop
            dinv[v] = rsqrtf((float)cval);  // cval >= 1 (self loop)
        }
        scur[t] = off;
        // sentinel pads (read H row N == zeros)
        for (int i = off + cval; i < off + pc; i++) csrc[i] = N;
    }
    __syncthreads();
    for (int i = t; i < m; i += 1024) {
        unsigned pk = pairs[ebeg + i];
        int slot = atomicAdd(&scur[pk >> 24], 1);
        csrc[slot] = (int)(pk & 0xFFFFFFu);
    }
}

// H[row] = dinv[row] * (X[row] @ W) via mfma_f32_16x16x32_bf16.
// Also writes an all-zero row at index N (sentinel target for csrc pads).
template <bool BF16IN>
__global__ __launch_bounds__(256) void k_gemm(const void* __restrict__ Xv,
                                              const float* __restrict__ W,
                                              const float* __restrict__ dinv,
                                              unsigned* __restrict__ Hout,
                                              int N, int nSlabs, int slabStride) {
    __shared__ float SMEM[4224];  // 4096 W staging, then 4 x (16x66) transpose
    int t = threadIdx.x;
    int lane = t & 63, w = t >> 6;
    int nn = lane & 15, kq = lane >> 4;

    for (int i = t; i < 1024; i += 256) ((float4*)SMEM)[i] = ((const float4*)W)[i];
    __syncthreads();
    bf16x8 Bf[2][4];
    #pragma unroll
    for (int kt = 0; kt < 2; kt++) {
        #pragma unroll
        for (int ct = 0; ct < 4; ct++) {
            union { bf16x8 v; unsigned short s[8]; } u;
            #pragma unroll
            for (int j = 0; j < 8; j++) {
                int k = kt * 32 + kq * 8 + j;
                u.s[j] = (unsigned short)bf16_rne(SMEM[k * 64 + ct * 16 + nn]);
            }
            Bf[kt][ct] = u.v;
        }
    }
    __syncthreads();  // W region dead; SMEM becomes transpose scratch

    float* outT = SMEM + w * 1056;  // 16 rows x 66 floats

    for (int slab = blockIdx.x * 4 + w; slab < nSlabs; slab += slabStride) {
        int row0 = slab * 16;
        int rowA = min(row0 + nn, N - 1);
        bf16x8 A0, A1;
        if (BF16IN) {
            const uint4* X = (const uint4*)Xv;  // row = 8 uint4
            union { uint4 u; bf16x8 v; } a0, a1;
            a0.u = X[(size_t)rowA * 8 + kq];
            a1.u = X[(size_t)rowA * 8 + 4 + kq];
            A0 = a0.v; A1 = a1.v;
        } else {
            const float4* X = (const float4*)Xv;  // row = 16 float4
            float4 f0 = X[(size_t)rowA * 16 + kq * 2];
            float4 f1 = X[(size_t)rowA * 16 + kq * 2 + 1];
            float4 f2 = X[(size_t)rowA * 16 + 8 + kq * 2];
            float4 f3 = X[(size_t)rowA * 16 + 8 + kq * 2 + 1];
            union { bf16x8 v; unsigned short s[8]; } a0, a1;
            a0.s[0] = (unsigned short)bf16_rne(f0.x); a0.s[1] = (unsigned short)bf16_rne(f0.y);
            a0.s[2] = (unsigned short)bf16_rne(f0.z); a0.s[3] = (unsigned short)bf16_rne(f0.w);
            a0.s[4] = (unsigned short)bf16_rne(f1.x); a0.s[5] = (unsigned short)bf16_rne(f1.y);
            a0.s[6] = (unsigned short)bf16_rne(f1.z); a0.s[7] = (unsigned short)bf16_rne(f1.w);
            a1.s[0] = (unsigned short)bf16_rne(f2.x); a1.s[1] = (unsigned short)bf16_rne(f2.y);
            a1.s[2] = (unsigned short)bf16_rne(f2.z); a1.s[3] = (unsigned short)bf16_rne(f2.w);
            a1.s[4] = (unsigned short)bf16_rne(f3.x); a1.s[5] = (unsigned short)bf16_rne(f3.y);
            a1.s[6] = (unsigned short)bf16_rne(f3.z); a1.s[7] = (unsigned short)bf16_rne(f3.w);
            A0 = a0.v; A1 = a1.v;
        }
        float dvm = dinv[rowA];

        f32x4 acc[4];
        #pragma unroll
        for (int ct = 0; ct < 4; ct++) acc[ct] = (f32x4){0.f, 0.f, 0.f, 0.f};
        #pragma unroll
        for (int ct = 0; ct < 4; ct++) {
            acc[ct] = __builtin_amdgcn_mfma_f32_16x16x32_bf16(A0, Bf[0][ct], acc[ct], 0, 0, 0);
            acc[ct] = __builtin_amdgcn_mfma_f32_16x16x32_bf16(A1, Bf[1][ct], acc[ct], 0, 0, 0);
        }

        #pragma unroll
        for (int reg = 0; reg < 4; reg++) {
            int r = kq * 4 + reg;
            float dv = __shfl(dvm, r);  // lane r holds dinv[row0+r]
            #pragma unroll
            for (int ct = 0; ct < 4; ct++) {
                outT[r * 66 + ct * 16 + nn] = acc[ct][reg] * dv;
            }
        }
        int rr = lane >> 2;        // 4 lanes per row
        int c0 = (lane & 3) * 16;  // 16 cols per lane
        int orow = row0 + rr;
        if (orow < N) {
            unsigned pk[8];
            #pragma unroll
            for (int i = 0; i < 8; i++) {
                float lo = outT[rr * 66 + c0 + 2 * i];
                float hi = outT[rr * 66 + c0 + 2 * i + 1];
                pk[i] = bf16_rne(lo) | (bf16_rne(hi) << 16);
            }
            uint4* dst = (uint4*)Hout + (size_t)orow * 8 + (lane & 3) * 2;
            dst[0] = make_uint4(pk[0], pk[1], pk[2], pk[3]);
            dst[1] = make_uint4(pk[4], pk[5], pk[6], pk[7]);
        } else if (orow == N) {  // zero sentinel row
            uint4* dst = (uint4*)Hout + (size_t)N * 8 + (lane & 3) * 2;
            dst[0] = make_uint4(0, 0, 0, 0);
            dst[1] = make_uint4(0, 0, 0, 0);
        }
    }
}

// out[v] = epi( dinv[v] * sum_{j in CSR[v]} H[src_j] + bias )
// One node per 8-lane group (8 nodes per wave, 32 per block).
// Lane fl = t&7 owns feats 8*fl..8*fl+7 (one uint4 of the bf16 row) ->
// accumulators are lane-private, no cross-lane reduction. csrc consumed as
// an int2 stream (cnt rounded to x2, sentinel row N = zeros), prefetched
// 1-deep. 32-bit byte offsets into H for saddr-form loads.
template <bool RELU_BF16OUT>
__global__ __launch_bounds__(256) void k_agg(const uint4* __restrict__ H,
                                             const int* __restrict__ offsets,
                                             const int* __restrict__ cnt,
                                             const int* __restrict__ csrc,
                                             const float* __restrict__ dinv,
                                             const float* __restrict__ bias,
                                             void* __restrict__ outv, int N) {
    int t = threadIdx.x;
    int fl = t & 7;                       // feature group: feats 8*fl..8*fl+7
    int v = blockIdx.x * NPB + (t >> 3);
    if (v >= N) return;
    int beg = offsets[v];                 // 16-aligned
    int deg = cnt[v];                     // true count rounded up to x2
    const int2* cs2 = (const int2*)(csrc + beg);
    const char* hb = (const char*)H + ((unsigned)fl << 4);

    float a0 = 0.f, a1 = 0.f, a2 = 0.f, a3 = 0.f;
    float a4 = 0.f, a5 = 0.f, a6 = 0.f, a7 = 0.f;

#define ACC8(R) do {                                                        \
        uint4 dd = *(const uint4*)(hb + ((unsigned)(R) << 7));              \
        a0 += bf16_lo(dd.x); a1 += bf16_hi(dd.x);                           \
        a2 += bf16_lo(dd.y); a3 += bf16_hi(dd.y);                           \
        a4 += bf16_lo(dd.z); a5 += bf16_hi(dd.z);                           \
        a6 += bf16_lo(dd.w); a7 += bf16_hi(dd.w);                           \
    } while (0)

    int2 ss = cs2[0];                     // deg >= 2 always (self loop + pad)
    for (int j = 2; j < deg; j += 2) {
        int2 nx = cs2[j >> 1];            // independent: issues before adds
        ACC8(ss.x);
        ACC8(ss.y);
        ss = nx;
    }
    ACC8(ss.x);
    ACC8(ss.y);
#undef ACC8

    float dv = dinv[v];
    const float4* b4 = (const float4*)bias;
    float4 bA = b4[fl * 2];
    float4 bB = b4[fl * 2 + 1];
    float r0 = fmaf(dv, a0, bA.x);
    float r1 = fmaf(dv, a1, bA.y);
    float r2 = fmaf(dv, a2, bA.z);
    float r3 = fmaf(dv, a3, bA.w);
    float r4 = fmaf(dv, a4, bB.x);
    float r5 = fmaf(dv, a5, bB.y);
    float r6 = fmaf(dv, a6, bB.z);
    float r7 = fmaf(dv, a7, bB.w);
    if (RELU_BF16OUT) {
        r0 = fmaxf(r0, 0.f); r1 = fmaxf(r1, 0.f);
        r2 = fmaxf(r2, 0.f); r3 = fmaxf(r3, 0.f);
        r4 = fmaxf(r4, 0.f); r5 = fmaxf(r5, 0.f);
        r6 = fmaxf(r6, 0.f); r7 = fmaxf(r7, 0.f);
        uint4 pk;
        pk.x = bf16_rne(r0) | (bf16_rne(r1) << 16);
        pk.y = bf16_rne(r2) | (bf16_rne(r3) << 16);
        pk.z = bf16_rne(r4) | (bf16_rne(r5) << 16);
        pk.w = bf16_rne(r6) | (bf16_rne(r7) << 16);
        ((uint4*)outv)[(size_t)v * 8 + fl] = pk;
    } else {
        float4* o = (float4*)outv + (size_t)v * 16 + fl * 2;
        o[0] = make_float4(r0, r1, r2, r3);
        o[1] = make_float4(r4, r5, r6, r7);
    }
}

extern "C" void kernel_launch(void* const* d_in, const int* in_sizes, int n_in,
                              void* d_out, int out_size, void* d_ws, size_t ws_size,
                              hipStream_t stream) {
    const float* x  = (const float*)d_in[0];
    const int*   ei = (const int*)d_in[1];  // harness delivers int32
    const float* W1 = (const float*)d_in[2];
    const float* b1 = (const float*)d_in[3];
    const float* W2 = (const float*)d_in[4];
    const float* b2 = (const float*)d_in[5];
    float* out      = (float*)d_out;

    const int N = in_sizes[0] / 64;
    const int E = in_sizes[1] / 2;
    const int* row = ei;
    const int* col = ei + E;
    const int T = E + N;
    const int NB = (N + BSZ - 1) >> BSH;  // buckets
    const int numTiles = (T + PTILE - 1) / PTILE;

    char* p = (char*)d_ws;
    auto alloc = [&](size_t bytes) { void* r = (void*)p; p += (bytes + 255) & ~(size_t)255; return r; };
    int*      tcnt    = (int*)alloc((size_t)NB * numTiles * 4);
    int*      btot    = (int*)alloc((size_t)(NB + 1) * 4);
    int*      offsets = (int*)alloc((size_t)N * 4);
    int*      cnt     = (int*)alloc((size_t)N * 4);
    float*    dinv    = (float*)alloc((size_t)N * 4);
    unsigned* pairs   = (unsigned*)alloc((size_t)NB * CAP * 4);
    int*      csrc    = (int*)alloc(((size_t)NB * CROW + 64) * 4);
    unsigned* hbuf    = (unsigned*)alloc((size_t)(N + 16) * 32 * 4);  // bf16, +zero row
    unsigned* abuf    = (unsigned*)alloc((size_t)(N + 16) * 32 * 4);  // bf16, +zero row

    k_count<<<numTiles, 256, 0, stream>>>(col, E, N, NB, numTiles, tcnt);
    k_scan<<<1, 512, 0, stream>>>(tcnt, btot, NB, numTiles);
    k_scatter<<<numTiles, 256, 0, stream>>>(row, col, E, N, NB, numTiles, tcnt, pairs);
    k_bfill<<<NB, 1024, 0, stream>>>(pairs, btot, N, offsets, cnt, dinv, csrc);

    const int nSlabs = (N + 16) / 16;  // covers zero sentinel row N
    const int GEMM_BLOCKS = 1024;      // 4 waves each
    const int SLAB_STRIDE = GEMM_BLOCKS * 4;
    const int GB = (N + NPB - 1) / NPB;

    k_gemm<false><<<GEMM_BLOCKS, 256, 0, stream>>>(x, W1, dinv, hbuf, N, nSlabs, SLAB_STRIDE);
    k_agg<true><<<GB, 256, 0, stream>>>((const uint4*)hbuf, offsets, cnt, csrc, dinv, b1, abuf, N);
    k_gemm<true><<<GEMM_BLOCKS, 256, 0, stream>>>(abuf, W2, dinv, hbuf, N, nSlabs, SLAB_STRIDE);
    k_agg<false><<<GB, 256, 0, stream>>>((const uint4*)hbuf, offsets, cnt, csrc, dinv, b2, out, N);
}

// Round 4
// 204.130 us; speedup vs baseline: 2.0655x; 2.0655x over previous
//
#include <hip/hip_runtime.h>

// ---------------------------------------------------------------------------
// GCN 2-layer forward, round 16.
// Round-15 post-mortem: FAILED 201.3->421.6us. k_scan=223us: ONE block,
// thread-per-bucket serial 416-iter dependent load->store chain = unhidden
// global latency x416 (HBM 0.05%, VALU 0.004% -> chip idle). Architecture
// (atomic-free partition) retained; scan parallelization was the bug.
// By subtraction count+scatter ~30us (vs old k_part 33) -> also attacked.
// Round-16 delta:
//   * k_scan: block-per-bucket (NB blocks x 512 thr), wave-shuffle block
//     scan over tile counts with chunk carry. All L2-resident.
//   * tcnt layout flipped to TILE-MAJOR [tile][bucket]: k_count writes 391
//     contiguous ints/block (was 4B stores strided 1.6KB = 162K line RFOs);
//     k_scatter cursor loads contiguous. Only k_scan reads strided (L2).
//   * k_count/k_scatter at 512 threads (13 waves/CU at 416 blocks).
// gemm/agg/bfill byte-identical. Pipeline: count, scan, scatter, bfill,
// gemm1, agg1, gemm2, agg2.
// ---------------------------------------------------------------------------

#define NPB 32       // nodes per block (agg): 256 thr / 8-lane groups
#define BSH 8        // bucket shift: 256 nodes per bucket
#define BSZ 256
#define PTILE 4096   // messages per partition tile
#define CAP 6144     // fixed bucket capacity (slots), multiple of 16
#define PADALLOW 3856  // per-bucket csrc pad allowance (256*15 + 16)
#define CROW (CAP + PADALLOW)  // per-bucket csrc region

typedef __attribute__((ext_vector_type(8))) short bf16x8;
typedef __attribute__((ext_vector_type(4))) float f32x4;

__device__ __forceinline__ unsigned bf16_rne(float f) {
    unsigned b = __float_as_uint(f);
    return (b + 0x7fffu + ((b >> 16) & 1u)) >> 16;
}
__device__ __forceinline__ float bf16_lo(unsigned u) { return __uint_as_float(u << 16); }
__device__ __forceinline__ float bf16_hi(unsigned u) { return __uint_as_float(u & 0xffff0000u); }

// Per-tile bucket histogram. tcnt layout: [tile][bucket] (tile-major ->
// contiguous writes here, contiguous cursor loads in k_scatter).
__global__ __launch_bounds__(512) void k_count(const int* __restrict__ coli,
                                               int E, int N, int NB, int numTiles,
                                               int* __restrict__ tcnt) {
    __shared__ int hist[512];
    int t = threadIdx.x;
    int T = E + N;
    int tile = blockIdx.x;
    int tstart = tile * PTILE;
    int m = min(PTILE, T - tstart);
    for (int b = t; b < NB; b += 512) hist[b] = 0;
    __syncthreads();
    for (int i = t; i < m; i += 512) {
        int g = tstart + i;
        int c = (g < E) ? coli[g] : (g - E);
        atomicAdd(&hist[c >> BSH], 1);
    }
    __syncthreads();
    for (int b = t; b < NB; b += 512) tcnt[(size_t)tile * NB + b] = hist[b];
}

// Block-per-bucket exclusive scan over tiles (chunked, wave-shuffle).
// tcnt[tile][b] <- b*CAP + prefix; btot[b] = bucket total.
__global__ __launch_bounds__(512) void k_scan(int* __restrict__ tcnt,
                                              int* __restrict__ btot,
                                              int NB, int numTiles) {
    __shared__ int wsum[8];
    int b = blockIdx.x;
    int t = threadIdx.x;
    int lane = t & 63, wid = t >> 6;
    int base = 0;
    for (int c0 = 0; c0 < numTiles; c0 += 512) {
        int tt = c0 + t;
        int v = (tt < numTiles) ? tcnt[(size_t)tt * NB + b] : 0;
        int inc = v;
        #pragma unroll
        for (int d = 1; d < 64; d <<= 1) {
            int o = __shfl_up(inc, d);
            if (lane >= d) inc += o;
        }
        if (lane == 63) wsum[wid] = inc;
        __syncthreads();
        int woff = 0, ctot = 0;
        #pragma unroll
        for (int i = 0; i < 8; i++) {
            int s = wsum[i];
            if (i < wid) woff += s;
            ctot += s;
        }
        if (tt < numTiles) tcnt[(size_t)tt * NB + b] = b * CAP + base + woff + inc - v;
        base += ctot;
        __syncthreads();  // wsum reused next chunk
    }
    if (t == 0) btot[b] = base;
}

// Scatter pass: LDS cursors seeded from scanned bases; LDS-atomic rank;
// contiguous-per-(tile,bucket) writes into pairs. No global atomics.
__global__ __launch_bounds__(512) void k_scatter(const int* __restrict__ rowi,
                                                 const int* __restrict__ coli,
                                                 int E, int N, int NB, int numTiles,
                                                 const int* __restrict__ tcnt,
                                                 unsigned* __restrict__ pairs) {
    __shared__ int scur[512];
    int t = threadIdx.x;
    int T = E + N;
    int tile = blockIdx.x;
    int tstart = tile * PTILE;
    int m = min(PTILE, T - tstart);
    for (int b = t; b < NB; b += 512) scur[b] = tcnt[(size_t)tile * NB + b];
    __syncthreads();
    for (int i = t; i < m; i += 512) {
        int g = tstart + i;
        int r, c;
        if (g < E) { r = rowi[g]; c = coli[g]; }
        else       { r = g - E; c = r; }  // self loop
        int b = c >> BSH;
        int slot = atomicAdd(&scur[b], 1);
        pairs[slot] = (unsigned)r | ((unsigned)(c & (BSZ - 1)) << 24);
    }
}

// One block per bucket (1024 threads): histogram its <=256 nodes, scan PADDED
// counts (16-aligned offsets), emit CSR meta (cnt = true count rounded to x2),
// fill csrc + sentinel pads. Message count for bucket b = btot[b].
__global__ __launch_bounds__(1024) void k_bfill(const unsigned* __restrict__ pairs,
                                                const int* __restrict__ btot,
                                                int N,
                                                int* __restrict__ offsets,
                                                int* __restrict__ cnt,
                                                float* __restrict__ dinv,
                                                int* __restrict__ csrc) {
    __shared__ int scnt[BSZ];
    __shared__ int scur[BSZ];
    __shared__ int wsum[4];
    int b = blockIdx.x;
    int t = threadIdx.x;
    int ebeg = b * CAP;
    int m = btot[b];
    int pbase = b * CROW;  // 16-aligned per-bucket csrc region base
    if (t < BSZ) scnt[t] = 0;
    __syncthreads();
    for (int i = t; i < m; i += 1024) {
        atomicAdd(&scnt[pairs[ebeg + i] >> 24], 1);
    }
    __syncthreads();
    int cval = 0, pc = 0, inc = 0;
    int lane = t & 63, wid = t >> 6;
    if (t < BSZ) {
        cval = scnt[t];                 // true msg count (incl. self loop)
        pc = (cval + 15) & ~15;         // offset padding: multiple of 16
        inc = pc;
        #pragma unroll
        for (int d = 1; d < 64; d <<= 1) {
            int o = __shfl_up(inc, d);
            if (lane >= d) inc += o;
        }
        if (lane == 63) wsum[wid] = inc;
    }
    __syncthreads();
    if (t < BSZ) {
        int woff = 0;
        for (int i = 0; i < wid; i++) woff += wsum[i];
        int off = pbase + woff + inc - pc;  // padded CSR offset for node (b<<BSH)+t
        int v = (b << BSH) + t;
        if (v < N) {
            offsets[v] = off;
            cnt[v] = (cval + 1) & ~1;       // round to x2 for int2 agg loop
            dinv[v] = rsqrtf((float)cval);  // cval >= 1 (self loop)
        }
        scur[t] = off;
        // sentinel pads (read H row N == zeros)
        for (int i = off + cval; i < off + pc; i++) csrc[i] = N;
    }
    __syncthreads();
    for (int i = t; i < m; i += 1024) {
        unsigned pk = pairs[ebeg + i];
        int slot = atomicAdd(&scur[pk >> 24], 1);
        csrc[slot] = (int)(pk & 0xFFFFFFu);
    }
}

// H[row] = dinv[row] * (X[row] @ W) via mfma_f32_16x16x32_bf16.
// Also writes an all-zero row at index N (sentinel target for csrc pads).
template <bool BF16IN>
__global__ __launch_bounds__(256) void k_gemm(const void* __restrict__ Xv,
                                              const float* __restrict__ W,
                                              const float* __restrict__ dinv,
                                              unsigned* __restrict__ Hout,
                                              int N, int nSlabs, int slabStride) {
    __shared__ float SMEM[4224];  // 4096 W staging, then 4 x (16x66) transpose
    int t = threadIdx.x;
    int lane = t & 63, w = t >> 6;
    int nn = lane & 15, kq = lane >> 4;

    for (int i = t; i < 1024; i += 256) ((float4*)SMEM)[i] = ((const float4*)W)[i];
    __syncthreads();
    bf16x8 Bf[2][4];
    #pragma unroll
    for (int kt = 0; kt < 2; kt++) {
        #pragma unroll
        for (int ct = 0; ct < 4; ct++) {
            union { bf16x8 v; unsigned short s[8]; } u;
            #pragma unroll
            for (int j = 0; j < 8; j++) {
                int k = kt * 32 + kq * 8 + j;
                u.s[j] = (unsigned short)bf16_rne(SMEM[k * 64 + ct * 16 + nn]);
            }
            Bf[kt][ct] = u.v;
        }
    }
    __syncthreads();  // W region dead; SMEM becomes transpose scratch

    float* outT = SMEM + w * 1056;  // 16 rows x 66 floats

    for (int slab = blockIdx.x * 4 + w; slab < nSlabs; slab += slabStride) {
        int row0 = slab * 16;
        int rowA = min(row0 + nn, N - 1);
        bf16x8 A0, A1;
        if (BF16IN) {
            const uint4* X = (const uint4*)Xv;  // row = 8 uint4
            union { uint4 u; bf16x8 v; } a0, a1;
            a0.u = X[(size_t)rowA * 8 + kq];
            a1.u = X[(size_t)rowA * 8 + 4 + kq];
            A0 = a0.v; A1 = a1.v;
        } else {
            const float4* X = (const float4*)Xv;  // row = 16 float4
            float4 f0 = X[(size_t)rowA * 16 + kq * 2];
            float4 f1 = X[(size_t)rowA * 16 + kq * 2 + 1];
            float4 f2 = X[(size_t)rowA * 16 + 8 + kq * 2];
            float4 f3 = X[(size_t)rowA * 16 + 8 + kq * 2 + 1];
            union { bf16x8 v; unsigned short s[8]; } a0, a1;
            a0.s[0] = (unsigned short)bf16_rne(f0.x); a0.s[1] = (unsigned short)bf16_rne(f0.y);
            a0.s[2] = (unsigned short)bf16_rne(f0.z); a0.s[3] = (unsigned short)bf16_rne(f0.w);
            a0.s[4] = (unsigned short)bf16_rne(f1.x); a0.s[5] = (unsigned short)bf16_rne(f1.y);
            a0.s[6] = (unsigned short)bf16_rne(f1.z); a0.s[7] = (unsigned short)bf16_rne(f1.w);
            a1.s[0] = (unsigned short)bf16_rne(f2.x); a1.s[1] = (unsigned short)bf16_rne(f2.y);
            a1.s[2] = (unsigned short)bf16_rne(f2.z); a1.s[3] = (unsigned short)bf16_rne(f2.w);
            a1.s[4] = (unsigned short)bf16_rne(f3.x); a1.s[5] = (unsigned short)bf16_rne(f3.y);
            a1.s[6] = (unsigned short)bf16_rne(f3.z); a1.s[7] = (unsigned short)bf16_rne(f3.w);
            A0 = a0.v; A1 = a1.v;
        }
        float dvm = dinv[rowA];

        f32x4 acc[4];
        #pragma unroll
        for (int ct = 0; ct < 4; ct++) acc[ct] = (f32x4){0.f, 0.f, 0.f, 0.f};
        #pragma unroll
        for (int ct = 0; ct < 4; ct++) {
            acc[ct] = __builtin_amdgcn_mfma_f32_16x16x32_bf16(A0, Bf[0][ct], acc[ct], 0, 0, 0);
            acc[ct] = __builtin_amdgcn_mfma_f32_16x16x32_bf16(A1, Bf[1][ct], acc[ct], 0, 0, 0);
        }

        #pragma unroll
        for (int reg = 0; reg < 4; reg++) {
            int r = kq * 4 + reg;
            float dv = __shfl(dvm, r);  // lane r holds dinv[row0+r]
            #pragma unroll
            for (int ct = 0; ct < 4; ct++) {
                outT[r * 66 + ct * 16 + nn] = acc[ct][reg] * dv;
            }
        }
        int rr = lane >> 2;        // 4 lanes per row
        int c0 = (lane & 3) * 16;  // 16 cols per lane
        int orow = row0 + rr;
        if (orow < N) {
            unsigned pk[8];
            #pragma unroll
            for (int i = 0; i < 8; i++) {
                float lo = outT[rr * 66 + c0 + 2 * i];
                float hi = outT[rr * 66 + c0 + 2 * i + 1];
                pk[i] = bf16_rne(lo) | (bf16_rne(hi) << 16);
            }
            uint4* dst = (uint4*)Hout + (size_t)orow * 8 + (lane & 3) * 2;
            dst[0] = make_uint4(pk[0], pk[1], pk[2], pk[3]);
            dst[1] = make_uint4(pk[4], pk[5], pk[6], pk[7]);
        } else if (orow == N) {  // zero sentinel row
            uint4* dst = (uint4*)Hout + (size_t)N * 8 + (lane & 3) * 2;
            dst[0] = make_uint4(0, 0, 0, 0);
            dst[1] = make_uint4(0, 0, 0, 0);
        }
    }
}

// out[v] = epi( dinv[v] * sum_{j in CSR[v]} H[src_j] + bias )
// One node per 8-lane group (8 nodes per wave, 32 per block).
// Lane fl = t&7 owns feats 8*fl..8*fl+7 (one uint4 of the bf16 row) ->
// accumulators are lane-private, no cross-lane reduction. csrc consumed as
// an int2 stream (cnt rounded to x2, sentinel row N = zeros), prefetched
// 1-deep. 32-bit byte offsets into H for saddr-form loads.
template <bool RELU_BF16OUT>
__global__ __launch_bounds__(256) void k_agg(const uint4* __restrict__ H,
                                             const int* __restrict__ offsets,
                                             const int* __restrict__ cnt,
                                             const int* __restrict__ csrc,
                                             const float* __restrict__ dinv,
                                             const float* __restrict__ bias,
                                             void* __restrict__ outv, int N) {
    int t = threadIdx.x;
    int fl = t & 7;                       // feature group: feats 8*fl..8*fl+7
    int v = blockIdx.x * NPB + (t >> 3);
    if (v >= N) return;
    int beg = offsets[v];                 // 16-aligned
    int deg = cnt[v];                     // true count rounded up to x2
    const int2* cs2 = (const int2*)(csrc + beg);
    const char* hb = (const char*)H + ((unsigned)fl << 4);

    float a0 = 0.f, a1 = 0.f, a2 = 0.f, a3 = 0.f;
    float a4 = 0.f, a5 = 0.f, a6 = 0.f, a7 = 0.f;

#define ACC8(R) do {                                                        \
        uint4 dd = *(const uint4*)(hb + ((unsigned)(R) << 7));              \
        a0 += bf16_lo(dd.x); a1 += bf16_hi(dd.x);                           \
        a2 += bf16_lo(dd.y); a3 += bf16_hi(dd.y);                           \
        a4 += bf16_lo(dd.z); a5 += bf16_hi(dd.z);                           \
        a6 += bf16_lo(dd.w); a7 += bf16_hi(dd.w);                           \
    } while (0)

    int2 ss = cs2[0];                     // deg >= 2 always (self loop + pad)
    for (int j = 2; j < deg; j += 2) {
        int2 nx = cs2[j >> 1];            // independent: issues before adds
        ACC8(ss.x);
        ACC8(ss.y);
        ss = nx;
    }
    ACC8(ss.x);
    ACC8(ss.y);
#undef ACC8

    float dv = dinv[v];
    const float4* b4 = (const float4*)bias;
    float4 bA = b4[fl * 2];
    float4 bB = b4[fl * 2 + 1];
    float r0 = fmaf(dv, a0, bA.x);
    float r1 = fmaf(dv, a1, bA.y);
    float r2 = fmaf(dv, a2, bA.z);
    float r3 = fmaf(dv, a3, bA.w);
    float r4 = fmaf(dv, a4, bB.x);
    float r5 = fmaf(dv, a5, bB.y);
    float r6 = fmaf(dv, a6, bB.z);
    float r7 = fmaf(dv, a7, bB.w);
    if (RELU_BF16OUT) {
        r0 = fmaxf(r0, 0.f); r1 = fmaxf(r1, 0.f);
        r2 = fmaxf(r2, 0.f); r3 = fmaxf(r3, 0.f);
        r4 = fmaxf(r4, 0.f); r5 = fmaxf(r5, 0.f);
        r6 = fmaxf(r6, 0.f); r7 = fmaxf(r7, 0.f);
        uint4 pk;
        pk.x = bf16_rne(r0) | (bf16_rne(r1) << 16);
        pk.y = bf16_rne(r2) | (bf16_rne(r3) << 16);
        pk.z = bf16_rne(r4) | (bf16_rne(r5) << 16);
        pk.w = bf16_rne(r6) | (bf16_rne(r7) << 16);
        ((uint4*)outv)[(size_t)v * 8 + fl] = pk;
    } else {
        float4* o = (float4*)outv + (size_t)v * 16 + fl * 2;
        o[0] = make_float4(r0, r1, r2, r3);
        o[1] = make_float4(r4, r5, r6, r7);
    }
}

extern "C" void kernel_launch(void* const* d_in, const int* in_sizes, int n_in,
                              void* d_out, int out_size, void* d_ws, size_t ws_size,
                              hipStream_t stream) {
    const float* x  = (const float*)d_in[0];
    const int*   ei = (const int*)d_in[1];  // harness delivers int32
    const float* W1 = (const float*)d_in[2];
    const float* b1 = (const float*)d_in[3];
    const float* W2 = (const float*)d_in[4];
    const float* b2 = (const float*)d_in[5];
    float* out      = (float*)d_out;

    const int N = in_sizes[0] / 64;
    const int E = in_sizes[1] / 2;
    const int* row = ei;
    const int* col = ei + E;
    const int T = E + N;
    const int NB = (N + BSZ - 1) >> BSH;  // buckets
    const int numTiles = (T + PTILE - 1) / PTILE;

    char* p = (char*)d_ws;
    auto alloc = [&](size_t bytes) { void* r = (void*)p; p += (bytes + 255) & ~(size_t)255; return r; };
    int*      tcnt    = (int*)alloc((size_t)NB * numTiles * 4);
    int*      btot    = (int*)alloc((size_t)(NB + 1) * 4);
    int*      offsets = (int*)alloc((size_t)N * 4);
    int*      cnt     = (int*)alloc((size_t)N * 4);
    float*    dinv    = (float*)alloc((size_t)N * 4);
    unsigned* pairs   = (unsigned*)alloc((size_t)NB * CAP * 4);
    int*      csrc    = (int*)alloc(((size_t)NB * CROW + 64) * 4);
    unsigned* hbuf    = (unsigned*)alloc((size_t)(N + 16) * 32 * 4);  // bf16, +zero row
    unsigned* abuf    = (unsigned*)alloc((size_t)(N + 16) * 32 * 4);  // bf16, +zero row

    k_count<<<numTiles, 512, 0, stream>>>(col, E, N, NB, numTiles, tcnt);
    k_scan<<<NB, 512, 0, stream>>>(tcnt, btot, NB, numTiles);
    k_scatter<<<numTiles, 512, 0, stream>>>(row, col, E, N, NB, numTiles, tcnt, pairs);
    k_bfill<<<NB, 1024, 0, stream>>>(pairs, btot, N, offsets, cnt, dinv, csrc);

    const int nSlabs = (N + 16) / 16;  // covers zero sentinel row N
    const int GEMM_BLOCKS = 1024;      // 4 waves each
    const int SLAB_STRIDE = GEMM_BLOCKS * 4;
    const int GB = (N + NPB - 1) / NPB;

    k_gemm<false><<<GEMM_BLOCKS, 256, 0, stream>>>(x, W1, dinv, hbuf, N, nSlabs, SLAB_STRIDE);
    k_agg<true><<<GB, 256, 0, stream>>>((const uint4*)hbuf, offsets, cnt, csrc, dinv, b1, abuf, N);
    k_gemm<true><<<GEMM_BLOCKS, 256, 0, stream>>>(abuf, W2, dinv, hbuf, N, nSlabs, SLAB_STRIDE);
    k_agg<false><<<GB, 256, 0, stream>>>((const uint4*)hbuf, offsets, cnt, csrc, dinv, b2, out, N);
}

// Round 5
// 197.958 us; speedup vs baseline: 2.1299x; 1.0312x over previous
//
#include <hip/hip_runtime.h>

// ---------------------------------------------------------------------------
// GCN 2-layer forward, round 17.
// Round-16 post-mortem: NEUTRAL 204.1 (vs 201.3 r14). Parallel k_scan fixed
// the r15 disaster, but partition ~36us ~= old k_part. Revised theory:
// UNCOALESCED 4B GLOBAL WRITES dominate scatter AND bfill. Evidence: r13
// k_part WRITE_SIZE 31.3MB for a 6.8MB pairs payload (4.6x amplification);
// lane-to-lane scattered stores = 64 separate 4B L2 transactions per wave,
// ~1.7M line-ops/pass at ~77G/s ~= 20us each.
// Round-17 delta:
//   * k_scatter v2: LDS counting sort per tile (hist -> block scan -> place
//     into LDS sorted buffer) then COALESCED stream-out of pairs.
//   * k_bfill v2: build the bucket's whole padded csrc region (<=40KB) in
//     LDS, then one coalesced LDS->global copy.
//   * k_count/k_scan/gemm/agg byte-identical.
// Pipeline: count, scan, scatter, bfill, gemm1, agg1, gemm2, agg2.
// ---------------------------------------------------------------------------

#define NPB 32       // nodes per block (agg): 256 thr / 8-lane groups
#define BSH 8        // bucket shift: 256 nodes per bucket
#define BSZ 256
#define PTILE 4096   // messages per partition tile
#define CAP 6144     // fixed bucket capacity (slots), multiple of 16
#define PADALLOW 3856  // per-bucket csrc pad allowance (256*15 + 16)
#define CROW (CAP + PADALLOW)  // per-bucket csrc region

typedef __attribute__((ext_vector_type(8))) short bf16x8;
typedef __attribute__((ext_vector_type(4))) float f32x4;

__device__ __forceinline__ unsigned bf16_rne(float f) {
    unsigned b = __float_as_uint(f);
    return (b + 0x7fffu + ((b >> 16) & 1u)) >> 16;
}
__device__ __forceinline__ float bf16_lo(unsigned u) { return __uint_as_float(u << 16); }
__device__ __forceinline__ float bf16_hi(unsigned u) { return __uint_as_float(u & 0xffff0000u); }

// Per-tile bucket histogram. tcnt layout: [tile][bucket] (tile-major ->
// contiguous writes here, contiguous cursor loads in k_scatter).
__global__ __launch_bounds__(512) void k_count(const int* __restrict__ coli,
                                               int E, int N, int NB, int numTiles,
                                               int* __restrict__ tcnt) {
    __shared__ int hist[512];
    int t = threadIdx.x;
    int T = E + N;
    int tile = blockIdx.x;
    int tstart = tile * PTILE;
    int m = min(PTILE, T - tstart);
    for (int b = t; b < NB; b += 512) hist[b] = 0;
    __syncthreads();
    for (int i = t; i < m; i += 512) {
        int g = tstart + i;
        int c = (g < E) ? coli[g] : (g - E);
        atomicAdd(&hist[c >> BSH], 1);
    }
    __syncthreads();
    for (int b = t; b < NB; b += 512) tcnt[(size_t)tile * NB + b] = hist[b];
}

// Block-per-bucket exclusive scan over tiles (chunked, wave-shuffle).
// tcnt[tile][b] <- b*CAP + prefix; btot[b] = bucket total.
__global__ __launch_bounds__(512) void k_scan(int* __restrict__ tcnt,
                                              int* __restrict__ btot,
                                              int NB, int numTiles) {
    __shared__ int wsum[8];
    int b = blockIdx.x;
    int t = threadIdx.x;
    int lane = t & 63, wid = t >> 6;
    int base = 0;
    for (int c0 = 0; c0 < numTiles; c0 += 512) {
        int tt = c0 + t;
        int v = (tt < numTiles) ? tcnt[(size_t)tt * NB + b] : 0;
        int inc = v;
        #pragma unroll
        for (int d = 1; d < 64; d <<= 1) {
            int o = __shfl_up(inc, d);
            if (lane >= d) inc += o;
        }
        if (lane == 63) wsum[wid] = inc;
        __syncthreads();
        int woff = 0, ctot = 0;
        #pragma unroll
        for (int i = 0; i < 8; i++) {
            int s = wsum[i];
            if (i < wid) woff += s;
            ctot += s;
        }
        if (tt < numTiles) tcnt[(size_t)tt * NB + b] = b * CAP + base + woff + inc - v;
        base += ctot;
        __syncthreads();  // wsum reused next chunk
    }
    if (t == 0) btot[b] = base;
}

// Scatter pass v2: LDS counting sort per tile, then COALESCED pairs writes.
// hist -> block scan (lbase) -> place into LDS sorted[] -> stream out in
// position order (consecutive lanes hit consecutive slots of a bucket chunk).
__global__ __launch_bounds__(512) void k_scatter(const int* __restrict__ rowi,
                                                 const int* __restrict__ coli,
                                                 int E, int N, int NB, int numTiles,
                                                 const int* __restrict__ tcnt,
                                                 unsigned* __restrict__ pairs) {
    __shared__ int hist[512];            // counts, then local cursors
    __shared__ int lbase[512];           // local exclusive base per bucket
    __shared__ int gbase[512];           // global base per bucket (tcnt row)
    __shared__ unsigned sorted[PTILE];   // payloads in tile-sorted order
    __shared__ unsigned short sbkt[PTILE];  // bucket id per sorted slot
    __shared__ int wsum[8];
    int t = threadIdx.x;
    int T = E + N;
    int tile = blockIdx.x;
    int tstart = tile * PTILE;
    int m = min(PTILE, T - tstart);
    for (int b = t; b < NB; b += 512) {
        hist[b] = 0;
        gbase[b] = tcnt[(size_t)tile * NB + b];
    }
    __syncthreads();
    int c_reg[8];  // statically indexed (rule: no runtime-indexed reg arrays)
    #pragma unroll
    for (int k = 0; k < 8; k++) {
        int i = t + k * 512;
        int c = 0;
        if (i < m) {
            int g = tstart + i;
            c = (g < E) ? coli[g] : (g - E);
            atomicAdd(&hist[c >> BSH], 1);
        }
        c_reg[k] = c;
    }
    __syncthreads();
    // block exclusive scan over NB (<=512) bucket counts -> lbase
    {
        int lane = t & 63, wid = t >> 6;
        int v = (t < NB) ? hist[t] : 0;
        int inc = v;
        #pragma unroll
        for (int d = 1; d < 64; d <<= 1) {
            int o = __shfl_up(inc, d);
            if (lane >= d) inc += o;
        }
        if (lane == 63) wsum[wid] = inc;
        __syncthreads();
        int woff = 0;
        for (int i = 0; i < wid; i++) woff += wsum[i];
        if (t < NB) lbase[t] = woff + inc - v;
        __syncthreads();
    }
    for (int b = t; b < NB; b += 512) hist[b] = 0;  // reuse as cursors
    __syncthreads();
    #pragma unroll
    for (int k = 0; k < 8; k++) {
        int i = t + k * 512;
        if (i < m) {
            int g = tstart + i;
            int c = c_reg[k];
            int r = (g < E) ? rowi[g] : c;  // self-loop tail has r == c
            int b = c >> BSH;
            int lr = atomicAdd(&hist[b], 1);
            int pos = lbase[b] + lr;
            sorted[pos] = (unsigned)r | ((unsigned)(c & (BSZ - 1)) << 24);
            sbkt[pos] = (unsigned short)b;
        }
    }
    __syncthreads();
    for (int j = t; j < m; j += 512) {
        int b = sbkt[j];
        pairs[gbase[b] + (j - lbase[b])] = sorted[j];
    }
}

// One block per bucket (1024 threads): histogram its <=256 nodes, scan PADDED
// counts, build the ENTIRE padded csrc region in LDS (payload + sentinel
// pads), then one coalesced LDS->global copy. CSR meta as before.
__global__ __launch_bounds__(1024) void k_bfill(const unsigned* __restrict__ pairs,
                                                const int* __restrict__ btot,
                                                int N,
                                                int* __restrict__ offsets,
                                                int* __restrict__ cnt,
                                                float* __restrict__ dinv,
                                                int* __restrict__ csrc) {
    __shared__ int scnt[BSZ];
    __shared__ int scur[BSZ];
    __shared__ int wsum[4];
    __shared__ int scsrc[CROW];  // 40KB: full padded bucket region
    int b = blockIdx.x;
    int t = threadIdx.x;
    int ebeg = b * CAP;
    int m = btot[b];
    int pbase = b * CROW;  // 16-aligned per-bucket csrc region base
    if (t < BSZ) scnt[t] = 0;
    __syncthreads();
    for (int i = t; i < m; i += 1024) {
        atomicAdd(&scnt[pairs[ebeg + i] >> 24], 1);
    }
    __syncthreads();
    int cval = 0, pc = 0, inc = 0;
    int lane = t & 63, wid = t >> 6;
    if (t < BSZ) {
        cval = scnt[t];                 // true msg count (incl. self loop)
        pc = (cval + 15) & ~15;         // padding: multiple of 16
        inc = pc;
        #pragma unroll
        for (int d = 1; d < 64; d <<= 1) {
            int o = __shfl_up(inc, d);
            if (lane >= d) inc += o;
        }
        if (lane == 63) wsum[wid] = inc;
    }
    __syncthreads();
    if (t < BSZ) {
        int woff = 0;
        for (int i = 0; i < wid; i++) woff += wsum[i];
        int offl = woff + inc - pc;         // LOCAL padded offset
        int v = (b << BSH) + t;
        if (v < N) {
            offsets[v] = pbase + offl;
            cnt[v] = (cval + 1) & ~1;       // round to x2 for int2 agg loop
            dinv[v] = rsqrtf((float)cval);  // cval >= 1 (self loop)
        }
        scur[t] = offl;
        // sentinel pads (read H row N == zeros) -- in LDS
        for (int i = offl + cval; i < offl + pc; i++) scsrc[i] = N;
    }
    __syncthreads();
    for (int i = t; i < m; i += 1024) {
        unsigned pk = pairs[ebeg + i];
        int slot = atomicAdd(&scur[pk >> 24], 1);
        scsrc[slot] = (int)(pk & 0xFFFFFFu);
    }
    __syncthreads();
    int tot = wsum[0] + wsum[1] + wsum[2] + wsum[3];  // total padded length
    for (int j = t; j < tot; j += 1024) csrc[pbase + j] = scsrc[j];
}

// H[row] = dinv[row] * (X[row] @ W) via mfma_f32_16x16x32_bf16.
// Also writes an all-zero row at index N (sentinel target for csrc pads).
template <bool BF16IN>
__global__ __launch_bounds__(256) void k_gemm(const void* __restrict__ Xv,
                                              const float* __restrict__ W,
                                              const float* __restrict__ dinv,
                                              unsigned* __restrict__ Hout,
                                              int N, int nSlabs, int slabStride) {
    __shared__ float SMEM[4224];  // 4096 W staging, then 4 x (16x66) transpose
    int t = threadIdx.x;
    int lane = t & 63, w = t >> 6;
    int nn = lane & 15, kq = lane >> 4;

    for (int i = t; i < 1024; i += 256) ((float4*)SMEM)[i] = ((const float4*)W)[i];
    __syncthreads();
    bf16x8 Bf[2][4];
    #pragma unroll
    for (int kt = 0; kt < 2; kt++) {
        #pragma unroll
        for (int ct = 0; ct < 4; ct++) {
            union { bf16x8 v; unsigned short s[8]; } u;
            #pragma unroll
            for (int j = 0; j < 8; j++) {
                int k = kt * 32 + kq * 8 + j;
                u.s[j] = (unsigned short)bf16_rne(SMEM[k * 64 + ct * 16 + nn]);
            }
            Bf[kt][ct] = u.v;
        }
    }
    __syncthreads();  // W region dead; SMEM becomes transpose scratch

    float* outT = SMEM + w * 1056;  // 16 rows x 66 floats

    for (int slab = blockIdx.x * 4 + w; slab < nSlabs; slab += slabStride) {
        int row0 = slab * 16;
        int rowA = min(row0 + nn, N - 1);
        bf16x8 A0, A1;
        if (BF16IN) {
            const uint4* X = (const uint4*)Xv;  // row = 8 uint4
            union { uint4 u; bf16x8 v; } a0, a1;
            a0.u = X[(size_t)rowA * 8 + kq];
            a1.u = X[(size_t)rowA * 8 + 4 + kq];
            A0 = a0.v; A1 = a1.v;
        } else {
            const float4* X = (const float4*)Xv;  // row = 16 float4
            float4 f0 = X[(size_t)rowA * 16 + kq * 2];
            float4 f1 = X[(size_t)rowA * 16 + kq * 2 + 1];
            float4 f2 = X[(size_t)rowA * 16 + 8 + kq * 2];
            float4 f3 = X[(size_t)rowA * 16 + 8 + kq * 2 + 1];
            union { bf16x8 v; unsigned short s[8]; } a0, a1;
            a0.s[0] = (unsigned short)bf16_rne(f0.x); a0.s[1] = (unsigned short)bf16_rne(f0.y);
            a0.s[2] = (unsigned short)bf16_rne(f0.z); a0.s[3] = (unsigned short)bf16_rne(f0.w);
            a0.s[4] = (unsigned short)bf16_rne(f1.x); a0.s[5] = (unsigned short)bf16_rne(f1.y);
            a0.s[6] = (unsigned short)bf16_rne(f1.z); a0.s[7] = (unsigned short)bf16_rne(f1.w);
            a1.s[0] = (unsigned short)bf16_rne(f2.x); a1.s[1] = (unsigned short)bf16_rne(f2.y);
            a1.s[2] = (unsigned short)bf16_rne(f2.z); a1.s[3] = (unsigned short)bf16_rne(f2.w);
            a1.s[4] = (unsigned short)bf16_rne(f3.x); a1.s[5] = (unsigned short)bf16_rne(f3.y);
            a1.s[6] = (unsigned short)bf16_rne(f3.z); a1.s[7] = (unsigned short)bf16_rne(f3.w);
            A0 = a0.v; A1 = a1.v;
        }
        float dvm = dinv[rowA];

        f32x4 acc[4];
        #pragma unroll
        for (int ct = 0; ct < 4; ct++) acc[ct] = (f32x4){0.f, 0.f, 0.f, 0.f};
        #pragma unroll
        for (int ct = 0; ct < 4; ct++) {
            acc[ct] = __builtin_amdgcn_mfma_f32_16x16x32_bf16(A0, Bf[0][ct], acc[ct], 0, 0, 0);
            acc[ct] = __builtin_amdgcn_mfma_f32_16x16x32_bf16(A1, Bf[1][ct], acc[ct], 0, 0, 0);
        }

        #pragma unroll
        for (int reg = 0; reg < 4; reg++) {
            int r = kq * 4 + reg;
            float dv = __shfl(dvm, r);  // lane r holds dinv[row0+r]
            #pragma unroll
            for (int ct = 0; ct < 4; ct++) {
                outT[r * 66 + ct * 16 + nn] = acc[ct][reg] * dv;
            }
        }
        int rr = lane >> 2;        // 4 lanes per row
        int c0 = (lane & 3) * 16;  // 16 cols per lane
        int orow = row0 + rr;
        if (orow < N) {
            unsigned pk[8];
            #pragma unroll
            for (int i = 0; i < 8; i++) {
                float lo = outT[rr * 66 + c0 + 2 * i];
                float hi = outT[rr * 66 + c0 + 2 * i + 1];
                pk[i] = bf16_rne(lo) | (bf16_rne(hi) << 16);
            }
            uint4* dst = (uint4*)Hout + (size_t)orow * 8 + (lane & 3) * 2;
            dst[0] = make_uint4(pk[0], pk[1], pk[2], pk[3]);
            dst[1] = make_uint4(pk[4], pk[5], pk[6], pk[7]);
        } else if (orow == N) {  // zero sentinel row
            uint4* dst = (uint4*)Hout + (size_t)N * 8 + (lane & 3) * 2;
            dst[0] = make_uint4(0, 0, 0, 0);
            dst[1] = make_uint4(0, 0, 0, 0);
        }
    }
}

// out[v] = epi( dinv[v] * sum_{j in CSR[v]} H[src_j] + bias )
// One node per 8-lane group (8 nodes per wave, 32 per block).
template <bool RELU_BF16OUT>
__global__ __launch_bounds__(256) void k_agg(const uint4* __restrict__ H,
                                             const int* __restrict__ offsets,
                                             const int* __restrict__ cnt,
                                             const int* __restrict__ csrc,
                                             const float* __restrict__ dinv,
                                             const float* __restrict__ bias,
                                             void* __restrict__ outv, int N) {
    int t = threadIdx.x;
    int fl = t & 7;                       // feature group: feats 8*fl..8*fl+7
    int v = blockIdx.x * NPB + (t >> 3);
    if (v >= N) return;
    int beg = offsets[v];                 // 16-aligned
    int deg = cnt[v];                     // true count rounded up to x2
    const int2* cs2 = (const int2*)(csrc + beg);
    const char* hb = (const char*)H + ((unsigned)fl << 4);

    float a0 = 0.f, a1 = 0.f, a2 = 0.f, a3 = 0.f;
    float a4 = 0.f, a5 = 0.f, a6 = 0.f, a7 = 0.f;

#define ACC8(R) do {                                                        \
        uint4 dd = *(const uint4*)(hb + ((unsigned)(R) << 7));              \
        a0 += bf16_lo(dd.x); a1 += bf16_hi(dd.x);                           \
        a2 += bf16_lo(dd.y); a3 += bf16_hi(dd.y);                           \
        a4 += bf16_lo(dd.z); a5 += bf16_hi(dd.z);                           \
        a6 += bf16_lo(dd.w); a7 += bf16_hi(dd.w);                           \
    } while (0)

    int2 ss = cs2[0];                     // deg >= 2 always (self loop + pad)
    for (int j = 2; j < deg; j += 2) {
        int2 nx = cs2[j >> 1];            // independent: issues before adds
        ACC8(ss.x);
        ACC8(ss.y);
        ss = nx;
    }
    ACC8(ss.x);
    ACC8(ss.y);
#undef ACC8

    float dv = dinv[v];
    const float4* b4 = (const float4*)bias;
    float4 bA = b4[fl * 2];
    float4 bB = b4[fl * 2 + 1];
    float r0 = fmaf(dv, a0, bA.x);
    float r1 = fmaf(dv, a1, bA.y);
    float r2 = fmaf(dv, a2, bA.z);
    float r3 = fmaf(dv, a3, bA.w);
    float r4 = fmaf(dv, a4, bB.x);
    float r5 = fmaf(dv, a5, bB.y);
    float r6 = fmaf(dv, a6, bB.z);
    float r7 = fmaf(dv, a7, bB.w);
    if (RELU_BF16OUT) {
        r0 = fmaxf(r0, 0.f); r1 = fmaxf(r1, 0.f);
        r2 = fmaxf(r2, 0.f); r3 = fmaxf(r3, 0.f);
        r4 = fmaxf(r4, 0.f); r5 = fmaxf(r5, 0.f);
        r6 = fmaxf(r6, 0.f); r7 = fmaxf(r7, 0.f);
        uint4 pk;
        pk.x = bf16_rne(r0) | (bf16_rne(r1) << 16);
        pk.y = bf16_rne(r2) | (bf16_rne(r3) << 16);
        pk.z = bf16_rne(r4) | (bf16_rne(r5) << 16);
        pk.w = bf16_rne(r6) | (bf16_rne(r7) << 16);
        ((uint4*)outv)[(size_t)v * 8 + fl] = pk;
    } else {
        float4* o = (float4*)outv + (size_t)v * 16 + fl * 2;
        o[0] = make_float4(r0, r1, r2, r3);
        o[1] = make_float4(r4, r5, r6, r7);
    }
}

extern "C" void kernel_launch(void* const* d_in, const int* in_sizes, int n_in,
                              void* d_out, int out_size, void* d_ws, size_t ws_size,
                              hipStream_t stream) {
    const float* x  = (const float*)d_in[0];
    const int*   ei = (const int*)d_in[1];  // harness delivers int32
    const float* W1 = (const float*)d_in[2];
    const float* b1 = (const float*)d_in[3];
    const float* W2 = (const float*)d_in[4];
    const float* b2 = (const float*)d_in[5];
    float* out      = (float*)d_out;

    const int N = in_sizes[0] / 64;
    const int E = in_sizes[1] / 2;
    const int* row = ei;
    const int* col = ei + E;
    const int T = E + N;
    const int NB = (N + BSZ - 1) >> BSH;  // buckets
    const int numTiles = (T + PTILE - 1) / PTILE;

    char* p = (char*)d_ws;
    auto alloc = [&](size_t bytes) { void* r = (void*)p; p += (bytes + 255) & ~(size_t)255; return r; };
    int*      tcnt    = (int*)alloc((size_t)NB * numTiles * 4);
    int*      btot    = (int*)alloc((size_t)(NB + 1) * 4);
    int*      offsets = (int*)alloc((size_t)N * 4);
    int*      cnt     = (int*)alloc((size_t)N * 4);
    float*    dinv    = (float*)alloc((size_t)N * 4);
    unsigned* pairs   = (unsigned*)alloc((size_t)NB * CAP * 4);
    int*      csrc    = (int*)alloc(((size_t)NB * CROW + 64) * 4);
    unsigned* hbuf    = (unsigned*)alloc((size_t)(N + 16) * 32 * 4);  // bf16, +zero row
    unsigned* abuf    = (unsigned*)alloc((size_t)(N + 16) * 32 * 4);  // bf16, +zero row

    k_count<<<numTiles, 512, 0, stream>>>(col, E, N, NB, numTiles, tcnt);
    k_scan<<<NB, 512, 0, stream>>>(tcnt, btot, NB, numTiles);
    k_scatter<<<numTiles, 512, 0, stream>>>(row, col, E, N, NB, numTiles, tcnt, pairs);
    k_bfill<<<NB, 1024, 0, stream>>>(pairs, btot, N, offsets, cnt, dinv, csrc);

    const int nSlabs = (N + 16) / 16;  // covers zero sentinel row N
    const int GEMM_BLOCKS = 1024;      // 4 waves each
    const int SLAB_STRIDE = GEMM_BLOCKS * 4;
    const int GB = (N + NPB - 1) / NPB;

    k_gemm<false><<<GEMM_BLOCKS, 256, 0, stream>>>(x, W1, dinv, hbuf, N, nSlabs, SLAB_STRIDE);
    k_agg<true><<<GB, 256, 0, stream>>>((const uint4*)hbuf, offsets, cnt, csrc, dinv, b1, abuf, N);
    k_gemm<true><<<GEMM_BLOCKS, 256, 0, stream>>>(abuf, W2, dinv, hbuf, N, nSlabs, SLAB_STRIDE);
    k_agg<false><<<GB, 256, 0, stream>>>((const uint4*)hbuf, offsets, cnt, csrc, dinv, b2, out, N);
}